// Round 18
// baseline (2409.362 us; speedup 1.0000x reference)
//
#include <hip/hip_runtime.h>
#include <math.h>

typedef unsigned short u16;
typedef u16 u16x8 __attribute__((ext_vector_type(8)));
typedef u16 u16x4 __attribute__((ext_vector_type(4)));
typedef short short8 __attribute__((ext_vector_type(8)));
typedef float f32x4 __attribute__((ext_vector_type(4)));

#define NE 768
#define NH 12
#define NL 12
#define NV 50257
#define NVP 50432   // NV padded to 256 multiple for the 256^2 LM-head GEMM
#define HD 64
#define DFF 3072
#define NB 2
#define SL 1024
#define TT 2048     // NB*SL tokens
#define QKVD 2304   // 3*NE

static __device__ __forceinline__ u16 f2bf(float f){
  unsigned int x; __builtin_memcpy(&x, &f, 4);
  x = (x + 0x7FFFu + ((x >> 16) & 1u)) >> 16;
  return (u16)x;
}

typedef const __attribute__((address_space(1))) unsigned int* gas1_t;
typedef __attribute__((address_space(3))) unsigned int* las3_t;
static __device__ __forceinline__ void gload16(const u16* g, u16* l){
  __builtin_amdgcn_global_load_lds((gas1_t)(const void*)g, (las3_t)(void*)l, 16, 0, 0);
}
// counted vmcnt wait: N loads may remain in flight (wave-uniform arg)
static __device__ __forceinline__ void waitvm(int n){
  switch (n){
    case 0: asm volatile("s_waitcnt vmcnt(0)" ::: "memory"); break;
    case 3: asm volatile("s_waitcnt vmcnt(3)" ::: "memory"); break;
    case 4: asm volatile("s_waitcnt vmcnt(4)" ::: "memory"); break;
    case 6: asm volatile("s_waitcnt vmcnt(6)" ::: "memory"); break;
    case 8: asm volatile("s_waitcnt vmcnt(8)" ::: "memory"); break;
    default: asm volatile("s_waitcnt vmcnt(9)" ::: "memory"); break;
  }
}

// ---------------- fp32 -> bf16 convert (vectorized) ----------------
__global__ void k_cvt4(const float4* __restrict__ in, u16x4* __restrict__ out, long n4){
  long i = (long)blockIdx.x * blockDim.x + threadIdx.x;
  long st = (long)gridDim.x * blockDim.x;
  for (; i < n4; i += st){
    float4 v = in[i];
    u16x4 o = { f2bf(v.x), f2bf(v.y), f2bf(v.z), f2bf(v.w) };
    out[i] = o;
  }
}

// ------ fp32 [L][K][N] -> bf16 [L][N][K] transpose-convert, all layers ------
// Vectorized: float4 reads, u16x4 writes. Tile: 32 K-rows x 128 N-cols.
__global__ __launch_bounds__(256) void k_transpose_cvt_all(const float* __restrict__ in0,
    u16* __restrict__ out0, int K, int N){
  __shared__ u16 tile[128][33];          // [n within 128][k within 32], +1 pad
  const float* in = in0 + (long)blockIdx.z * K * N;
  u16* out = out0 + (long)blockIdx.z * N * K;
  const int n0 = blockIdx.x * 128, k0 = blockIdx.y * 32;
  const int t = threadIdx.x;
#pragma unroll
  for (int i = 0; i < 4; ++i){
    int e = t + i * 256;                 // [0,1024)
    int r = e >> 5, c = e & 31;          // r: k-row [0,32), c: float4 col [0,32)
    float4 v = *(const float4*)(in + (long)(k0 + r) * N + n0 + c * 4);
    tile[c * 4 + 0][r] = f2bf(v.x);
    tile[c * 4 + 1][r] = f2bf(v.y);
    tile[c * 4 + 2][r] = f2bf(v.z);
    tile[c * 4 + 3][r] = f2bf(v.w);
  }
  __syncthreads();
#pragma unroll
  for (int i = 0; i < 4; ++i){
    int e = t + i * 256;                 // [0,1024)
    int nr = e >> 3, kc = e & 7;         // nr: n-row [0,128), kc: u16x4 chunk [0,8)
    u16x4 o = { tile[nr][kc * 4 + 0], tile[nr][kc * 4 + 1],
                tile[nr][kc * 4 + 2], tile[nr][kc * 4 + 3] };
    *(u16x4*)(out + (long)(n0 + nr) * K + k0 + kc * 4) = o;
  }
}

// ---------------- LayerNorm: f32 [TT][768] -> bf16 ----------------
__global__ __launch_bounds__(256) void k_layernorm(const float* __restrict__ x,
    const float* __restrict__ g, const float* __restrict__ b, u16* __restrict__ out){
  int row = blockIdx.x;
  const float* xr = x + (long)row * NE;
  int t = threadIdx.x;
  float v[3];
  v[0] = xr[t]; v[1] = xr[t + 256]; v[2] = xr[t + 512];
  float s = v[0] + v[1] + v[2];
  float sq = v[0]*v[0] + v[1]*v[1] + v[2]*v[2];
  __shared__ float red[8];
#pragma unroll
  for (int o = 32; o; o >>= 1){ s += __shfl_xor(s, o); sq += __shfl_xor(sq, o); }
  int wid = t >> 6, lane = t & 63;
  if (!lane){ red[wid] = s; red[4 + wid] = sq; }
  __syncthreads();
  s  = red[0] + red[1] + red[2] + red[3];
  sq = red[4] + red[5] + red[6] + red[7];
  float mean = s * (1.f / NE);
  float var  = sq * (1.f / NE) - mean * mean;
  float rs = rsqrtf(var + 1e-5f);
  u16* orow = out + (long)row * NE;
#pragma unroll
  for (int i = 0; i < 3; ++i){
    int c = t + i * 256;
    orow[c] = f2bf((v[i] - mean) * rs * g[c] + b[c]);
  }
}

// ---- split-K combine + LayerNorm fused (float4-vectorized): one block/row ----
__global__ __launch_bounds__(256) void k_combine_ln(float* __restrict__ h,
    const float* __restrict__ part, const float* __restrict__ bias, int nsplit,
    const float* __restrict__ g, const float* __restrict__ b, u16* __restrict__ aout){
  const int row = blockIdx.x;
  const int t = threadIdx.x;              // threads 0..191 each own one float4
  float4* hr4 = (float4*)(h + (long)row * NE);
  float4 v = {0.f, 0.f, 0.f, 0.f};
  float s = 0.f, sq = 0.f;
  if (t < NE / 4){
    v = hr4[t];
    float4 bb = ((const float4*)bias)[t];
    v.x += bb.x; v.y += bb.y; v.z += bb.z; v.w += bb.w;
    for (int sp = 0; sp < nsplit; ++sp){
      float4 pv = ((const float4*)(part + (long)sp * TT * NE + (long)row * NE))[t];
      v.x += pv.x; v.y += pv.y; v.z += pv.z; v.w += pv.w;
    }
    hr4[t] = v;
    s  = v.x + v.y + v.z + v.w;
    sq = v.x*v.x + v.y*v.y + v.z*v.z + v.w*v.w;
  }
  __shared__ float red[8];
#pragma unroll
  for (int o = 32; o; o >>= 1){ s += __shfl_xor(s, o); sq += __shfl_xor(sq, o); }
  int wid = t >> 6, lane = t & 63;
  if (!lane){ red[wid] = s; red[4 + wid] = sq; }
  __syncthreads();
  s  = red[0] + red[1] + red[2] + red[3];
  sq = red[4] + red[5] + red[6] + red[7];
  float mean = s * (1.f / NE);
  float var  = sq * (1.f / NE) - mean * mean;
  float rs = rsqrtf(var + 1e-5f);
  if (t < NE / 4){
    float4 gg = ((const float4*)g)[t];
    float4 b2 = ((const float4*)b)[t];
    u16x4 o4 = { f2bf((v.x - mean) * rs * gg.x + b2.x),
                 f2bf((v.y - mean) * rs * gg.y + b2.y),
                 f2bf((v.z - mean) * rs * gg.z + b2.z),
                 f2bf((v.w - mean) * rs * gg.w + b2.w) };
    ((u16x4*)(aout + (long)row * NE))[t] = o4;
  }
}

// ---------------- barrier-free fused causal flash attention ----------------
// 2-wave blocks, 32 q-rows per block, grid (24 bh, 32 q-tiles) heavy-first.
__global__ __launch_bounds__(128) void k_flash(const u16* __restrict__ qkv,
    const u16* __restrict__ vt, u16* __restrict__ out){
  __shared__ u16 Ps[2][16][72];          // wave-private P tile (q x kv)
  const int z = blockIdx.x;
  const int qt = gridDim.y - 1 - blockIdx.y;   // heavy q-tiles dispatch first
  const int b = z / NH, h = z % NH;
  const int t = threadIdx.x, lane = t & 63, wid = t >> 6;
  const int lr = lane & 15, lk = lane >> 4;
  const int qr0 = qt * 32 + wid * 16;    // wave's first q row
  const u16* Qp = qkv + (long)(b * SL + qr0 + lr) * QKVD + h * HD;
  short8 aq[2];
  aq[0] = *(const short8*)(Qp + lk * 8);
  aq[1] = *(const short8*)(Qp + 32 + lk * 8);
  const u16* Kb  = qkv + (long)(b * SL) * QKVD + NE + h * HD;
  const u16* Vtb = vt + (long)z * HD * SL;
  f32x4 o[4] = {};
  float m[4], l[4];
#pragma unroll
  for (int r = 0; r < 4; ++r){ m[r] = -3e38f; l[r] = 0.f; }
  const int nt = (qt * 32 + 31) / 64 + 1;
  for (int kt = 0; kt < nt; ++kt){
    const int kv0 = kt * 64;
    short8 kb[4][2];
#pragma unroll
    for (int j = 0; j < 4; ++j)
#pragma unroll
      for (int c = 0; c < 2; ++c)
        kb[j][c] = *(const short8*)(Kb + (long)(kv0 + j * 16 + lr) * QKVD + c * 32 + lk * 8);
    f32x4 s[4] = {};
#pragma unroll
    for (int c = 0; c < 2; ++c)
#pragma unroll
      for (int j = 0; j < 4; ++j)
        s[j] = __builtin_amdgcn_mfma_f32_16x16x32_bf16(aq[c], kb[j][c], s[j], 0, 0, 0);
    const bool dm = (kt == nt - 1);
#pragma unroll
    for (int r = 0; r < 4; ++r){
      const int row = qr0 + lk * 4 + r;
      float pm = -3e38f;
#pragma unroll
      for (int j = 0; j < 4; ++j){
        float v = s[j][r] * 0.125f;
        if (dm && (kv0 + j * 16 + lr > row)) v = -3e38f;
        s[j][r] = v;
        pm = fmaxf(pm, v);
      }
#pragma unroll
      for (int off = 1; off < 16; off <<= 1) pm = fmaxf(pm, __shfl_xor(pm, off));
      float mn = fmaxf(m[r], pm);
      float f = __expf(m[r] - mn);
      m[r] = mn;
      float ps = 0.f;
#pragma unroll
      for (int j = 0; j < 4; ++j){
        float pv = __expf(s[j][r] - mn);
        ps += pv;
        Ps[wid][lk * 4 + r][j * 16 + lr] = f2bf(pv);
      }
#pragma unroll
      for (int off = 1; off < 16; off <<= 1) ps += __shfl_xor(ps, off);
      l[r] = l[r] * f + ps;
#pragma unroll
      for (int j = 0; j < 4; ++j) o[j][r] *= f;
    }
#pragma unroll
    for (int c = 0; c < 2; ++c){
      short8 pa = *(const short8*)&Ps[wid][lr][c * 32 + lk * 8];
#pragma unroll
      for (int j = 0; j < 4; ++j){
        short8 vb = *(const short8*)(Vtb + (long)(j * 16 + lr) * SL + kv0 + c * 32 + lk * 8);
        o[j] = __builtin_amdgcn_mfma_f32_16x16x32_bf16(pa, vb, o[j], 0, 0, 0);
      }
    }
  }
  u16* O = out + (long)(b * SL) * NE + h * HD;
#pragma unroll
  for (int r = 0; r < 4; ++r){
    float inv = 1.f / l[r];
    const int row = qr0 + lk * 4 + r;
#pragma unroll
    for (int j = 0; j < 4; ++j)
      O[(long)row * NE + j * 16 + lr] = f2bf(o[j][r] * inv);
  }
}

// --- generic bf16 MFMA GEMM, 64x128 tile, B^T layout, 4-buf (depth-3) ring ---
// Parity-aware LDS swizzle: slot ^= (row>>1)&3 on both stage-source and read.
// modes: 2 bf16 +bias +gelu(erf), 3 f32 raw, 5 qkv: bf16 +bias, V cols scattered to vt
struct GemmP {
  const u16* A; const u16* B; void* C;
  const float* bias; u16* vt;
  int M, N, K, lda, ldb, ldc, mode;
  long zA, zB, zC;                       // per-blockIdx.z element offsets (split-K)
};

__global__ __launch_bounds__(256) void k_gemm_bt(GemmP p){
  __shared__ u16 As[4][64 * 32];
  __shared__ u16 Bs[4][128 * 32];
  // XCD-aware block swizzle (nwg is always a multiple of 8 here)
  const int nwg = gridDim.x * gridDim.y;
  const int orig = blockIdx.x + blockIdx.y * gridDim.x;
  const int wg = (orig & 7) * (nwg >> 3) + (orig >> 3);
  const int m0 = (wg % gridDim.x) * 64, n0 = (wg / gridDim.x) * 128;
  const u16* A = p.A + (long)blockIdx.z * p.zA;
  const u16* B = p.B + (long)blockIdx.z * p.zB;
  const long offC = (long)blockIdx.z * p.zC;
  const int t = threadIdx.x, lane = t & 63, wid = t >> 6;
  const int wm = (wid >> 1) * 32, wn = (wid & 1) * 64;
  const int lr = lane & 15, lk = lane >> 4;
  const int srow = t >> 2;               // [0,64)
  // pre-swizzled source slot: phys slot (t&3) holds logical slot (t&3)^((srow>>1)&3)
  const int sseg = ((t & 3) ^ ((srow >> 1) & 3)) * 8;
  const u16* Abase  = A + (long)(m0 + srow) * p.lda + sseg;
  const u16* Bbase  = B + (long)(n0 + srow) * p.ldb + sseg;
  const u16* Bbase2 = B + (long)(n0 + 64 + srow) * p.ldb + sseg;  // (row+64): same XOR
  auto stage = [&](int buf, int kt){     // 3 gload_lds per thread per K-tile
    gload16(Abase  + kt * 32, &As[buf][t * 8]);
    gload16(Bbase  + kt * 32, &Bs[buf][t * 8]);
    gload16(Bbase2 + kt * 32, &Bs[buf][(t + 256) * 8]);
  };
  f32x4 acc[2][4] = {};
  const int nk = p.K >> 5;               // always >= 2 here
  stage(0, 0);
  stage(1, 1);
  if (nk > 2) stage(2, 2);
  for (int kt = 0; kt < nk; ++kt){
    const int cur = kt & 3;
    if (kt + 3 < nk) stage((kt + 3) & 3, kt + 3);  // overwrite of (kt-1)&3: guarded
    // wait only this tile's 3 loads; leave up to 9 (tiles kt+1..kt+3) in flight
    int rem = nk - 1 - kt;
    waitvm(rem >= 3 ? 9 : rem == 2 ? 6 : rem == 1 ? 3 : 0);
    __builtin_amdgcn_s_barrier();        // all waves' tile-kt loads complete
    short8 af[2], bfr[4];
#pragma unroll
    for (int i = 0; i < 2; ++i){
      int r = wm + i * 16 + lr;
      af[i]  = *(const short8*)&As[cur][r * 32 + ((lk ^ ((r >> 1) & 3)) * 8)];
    }
#pragma unroll
    for (int j = 0; j < 4; ++j){
      int r = wn + j * 16 + lr;
      bfr[j] = *(const short8*)&Bs[cur][r * 32 + ((lk ^ ((r >> 1) & 3)) * 8)];
    }
#pragma unroll
    for (int i = 0; i < 2; ++i)
#pragma unroll
      for (int j = 0; j < 4; ++j)
        acc[i][j] = __builtin_amdgcn_mfma_f32_16x16x32_bf16(af[i], bfr[j], acc[i][j], 0, 0, 0);
    asm volatile("s_waitcnt lgkmcnt(0)" ::: "memory");  // ds_reads of buf done
    __builtin_amdgcn_s_barrier();        // before buf is restaged (3 iters later)
  }
#pragma unroll
  for (int i = 0; i < 2; ++i){
#pragma unroll
    for (int r = 0; r < 4; ++r){
      int row = m0 + wm + i * 16 + lk * 4 + r;
      if (row >= p.M) continue;
#pragma unroll
      for (int j = 0; j < 4; ++j){
        int col = n0 + wn + j * 16 + lr;
        if (col >= p.N) continue;
        float v = acc[i][j][r];
        long idx = offC + (long)row * p.ldc + col;
        if (p.mode == 5){
          v += p.bias[col];
          if (col >= 2 * NE){
            int d = col - 2 * NE;
            long vidx = (((long)(row >> 10) * NH + (d >> 6)) * HD + (d & 63)) * SL + (row & 1023);
            p.vt[vidx] = f2bf(v);
          } else {
            ((u16*)p.C)[idx] = f2bf(v);
          }
        } else if (p.mode == 2){
          v += p.bias[col];
          v = 0.5f * v * (1.f + erff(v * 0.70710678118f));
          ((u16*)p.C)[idx] = f2bf(v);
        } else {
          ((float*)p.C)[idx] = v;
        }
      }
    }
  }
}

static inline void gemm(hipStream_t s, const u16* A, int lda, const u16* B, int ldb,
    void* C, int ldc, int M, int N, int K, const float* bias, u16* vt, int mode,
    int gz = 1, long zA = 0, long zB = 0, long zC = 0){
  GemmP p{ A, B, C, bias, vt, M, N, K, lda, ldb, ldc, mode, zA, zB, zC };
  dim3 g(M / 64, (N + 127) / 128, gz);
  k_gemm_bt<<<g, 256, 0, s>>>(p);
}

// ======== 256x256 8-wave LM-head GEMM: BK=32, 2-buf (64 KB -> 2 blocks/CU) ========
// Parity-aware swizzle slot^((r>>1)&3) (r12-correctness-proven). Depth-1 counted
// vmcnt(4). No reg cap (r12's (512,4) spilled acc to scratch); ~112 VGPR -> 2
// blocks/CU co-residency hides the per-K-step barrier drain (m114 overlap).
__global__ __launch_bounds__(512, 1) void k_gemm256(const u16* __restrict__ A,
    const u16* __restrict__ B, float* __restrict__ C){
  __shared__ u16 As[2][256 * 32];
  __shared__ u16 Bs[2][256 * 32];
  const int gx = gridDim.x, nwg = gx * gridDim.y;
  const int orig = blockIdx.x + blockIdx.y * gx;
  const int wg = (orig & 7) * (nwg >> 3) + (orig >> 3);   // nwg % 8 == 0
  const int m0 = (wg % gx) * 256, n0 = (wg / gx) * 256;
  const int t = threadIdx.x, lane = t & 63;
  const int lr = lane & 15, lk = lane >> 4;
  const int wid = t >> 6, wr = wid >> 2, wc = wid & 3;    // wave tile 128x64
  // staging: 1024 chunks/tile (256 rows x 4 slots); thread covers chunks t, t+512.
  // phys slot pp holds logical slot pp^((r>>1)&3) via pre-swizzled global source.
  const u16* gA[2]; const u16* gB[2]; int ldst[2];
#pragma unroll
  for (int i = 0; i < 2; ++i){
    int idx = t + i * 512, r = idx >> 2, pp = idx & 3, sl = pp ^ ((r >> 1) & 3);
    gA[i] = A + (long)(m0 + r) * NE + sl * 8;
    gB[i] = B + (long)(n0 + r) * NE + sl * 8;
    ldst[i] = idx * 8;                   // u16 offset (linear dest)
  }
  auto stage = [&](int buf, int kt){     // 4 gload16 per thread per K-tile
#pragma unroll
    for (int i = 0; i < 2; ++i) gload16(gA[i] + kt * 32, &As[buf][ldst[i]]);
#pragma unroll
    for (int i = 0; i < 2; ++i) gload16(gB[i] + kt * 32, &Bs[buf][ldst[i]]);
  };
  f32x4 acc[8][4] = {};
  const int nk = NE / 32;                // 24 K-tiles
  stage(0, 0);
  for (int kt = 0; kt < nk; ++kt){
    const int buf = kt & 1;
    if (kt + 1 < nk){ stage(buf ^ 1, kt + 1); waitvm(4); }
    else            { waitvm(0); }
    __builtin_amdgcn_sched_barrier(0);
    __builtin_amdgcn_s_barrier();        // tile kt resident in As/Bs[buf]
    __builtin_amdgcn_sched_barrier(0);
    short8 bf[4];
#pragma unroll
    for (int nj = 0; nj < 4; ++nj){
      int r = wc * 64 + nj * 16 + lr;
      bf[nj] = *(const short8*)&Bs[buf][r * 32 + ((lk ^ ((r >> 1) & 3)) * 8)];
    }
    {
      short8 af[4];
#pragma unroll
      for (int mi = 0; mi < 4; ++mi){
        int r = wr * 128 + mi * 16 + lr;
        af[mi] = *(const short8*)&As[buf][r * 32 + ((lk ^ ((r >> 1) & 3)) * 8)];
      }
      __builtin_amdgcn_s_setprio(1);
#pragma unroll
      for (int mi = 0; mi < 4; ++mi)
#pragma unroll
        for (int nj = 0; nj < 4; ++nj)
          acc[mi][nj] = __builtin_amdgcn_mfma_f32_16x16x32_bf16(af[mi], bf[nj], acc[mi][nj], 0, 0, 0);
      __builtin_amdgcn_s_setprio(0);
    }
    {
      short8 af[4];
#pragma unroll
      for (int mi = 0; mi < 4; ++mi){
        int r = wr * 128 + (mi + 4) * 16 + lr;
        af[mi] = *(const short8*)&As[buf][r * 32 + ((lk ^ ((r >> 1) & 3)) * 8)];
      }
      __builtin_amdgcn_s_setprio(1);
#pragma unroll
      for (int mi = 0; mi < 4; ++mi)
#pragma unroll
        for (int nj = 0; nj < 4; ++nj)
          acc[mi + 4][nj] = __builtin_amdgcn_mfma_f32_16x16x32_bf16(af[mi], bf[nj], acc[mi + 4][nj], 0, 0, 0);
      __builtin_amdgcn_s_setprio(0);
    }
    asm volatile("s_waitcnt lgkmcnt(0)" ::: "memory");  // this wave's ds_reads done
    __builtin_amdgcn_sched_barrier(0);
    __builtin_amdgcn_s_barrier();        // all waves done with buf -> restage next iter
  }
#pragma unroll
  for (int mi = 0; mi < 8; ++mi)
#pragma unroll
    for (int r = 0; r < 4; ++r){
      int row = m0 + wr * 128 + mi * 16 + lk * 4 + r;
#pragma unroll
      for (int nj = 0; nj < 4; ++nj){
        int col = n0 + wc * 64 + nj * 16 + lr;
        if (col < NV) C[(long)row * NV + col] = acc[mi][nj][r];
      }
    }
}

extern "C" void kernel_launch(void* const* d_in, const int* in_sizes, int n_in,
                              void* d_out, int out_size, void* d_ws, size_t ws_size,
                              hipStream_t stream){
  (void)in_sizes; (void)n_in; (void)out_size; (void)ws_size;
  const float* x    = (const float*)d_in[0];
  const float* Wqkv = (const float*)d_in[1];
  const float* bqkv = (const float*)d_in[2];
  const float* Wo   = (const float*)d_in[3];
  const float* bo   = (const float*)d_in[4];
  const float* W1   = (const float*)d_in[5];
  const float* b1   = (const float*)d_in[6];
  const float* W2   = (const float*)d_in[7];
  const float* b2   = (const float*)d_in[8];
  const float* ln1g = (const float*)d_in[9];
  const float* ln1b = (const float*)d_in[10];
  const float* ln2g = (const float*)d_in[11];
  const float* ln2b = (const float*)d_in[12];
  const float* lnfg = (const float*)d_in[13];
  const float* lnfb = (const float*)d_in[14];
  const float* Wlm  = (const float*)d_in[15];

  char* ws = (char*)d_ws;
  size_t off = 0;
  auto alloc = [&](size_t bytes){ void* p = ws + off; off += (bytes + 255) & ~255UL; return p; };
  float* h      = (float*)alloc((size_t)TT * NE * 4);
  u16*   a      = (u16*)  alloc((size_t)TT * NE * 2);
  u16*   qkv    = (u16*)  alloc((size_t)TT * QKVD * 2);
  u16*   vtbuf  = (u16*)  alloc((size_t)NB * NH * HD * SL * 2);
  u16*   attno  = (u16*)  alloc((size_t)TT * NE * 2);
  u16*   ffm    = (u16*)  alloc((size_t)TT * DFF * 2);
  float* part   = (float*)alloc((size_t)4 * TT * NE * 4);
  u16*   wqkvT  = (u16*)  alloc((size_t)NL * QKVD * NE * 2);
  u16*   woT    = (u16*)  alloc((size_t)NL * NE * NE * 2);
  u16*   w1T    = (u16*)  alloc((size_t)NL * DFF * NE * 2);
  u16*   w2T    = (u16*)  alloc((size_t)NL * NE * DFF * 2);
  u16*   wlmB   = (u16*)  alloc((size_t)NVP * NE * 2);

  // h = x
  hipMemcpyAsync(h, x, (size_t)TT * NE * 4, hipMemcpyDeviceToDevice, stream);
  // weight conversions (vectorized transpose: grid N/128 x K/32 x NL)
  k_transpose_cvt_all<<<dim3(QKVD / 128, NE / 32, NL), 256, 0, stream>>>(Wqkv, wqkvT, NE, QKVD);
  k_transpose_cvt_all<<<dim3(NE / 128, NE / 32, NL),   256, 0, stream>>>(Wo,   woT,   NE, NE);
  k_transpose_cvt_all<<<dim3(DFF / 128, NE / 32, NL),  256, 0, stream>>>(W1,   w1T,   NE, DFF);
  k_transpose_cvt_all<<<dim3(NE / 128, DFF / 32, NL),  256, 0, stream>>>(W2,   w2T,   DFF, NE);
  k_cvt4<<<2048, 256, 0, stream>>>((const float4*)Wlm, (u16x4*)wlmB, (long)NV * NE / 4);
  hipMemsetAsync(wlmB + (size_t)NV * NE, 0, (size_t)(NVP - NV) * NE * 2, stream);

  // ln1 of layer 0
  k_layernorm<<<TT, 256, 0, stream>>>(h, ln1g, ln1b, a);

  for (int L = 0; L < NL; ++L){
    // qkv = a @ Wqkv + bqkv ; V columns scattered transposed into vtbuf
    gemm(stream, a, NE, wqkvT + (size_t)L * QKVD * NE, NE, qkv, QKVD, TT, QKVD, NE,
         bqkv + (size_t)L * QKVD, vtbuf, 5);
    // fused causal attention -> attno
    k_flash<<<dim3(NB * NH, SL / 32), 128, 0, stream>>>(qkv, vtbuf, attno);
    // proj: split-K x2 partials
    gemm(stream, attno, NE, woT + (size_t)L * NE * NE, NE, part, NE, TT, NE, 384,
         nullptr, nullptr, 3, 2, 384, 384, (long)TT * NE);
    // h += bo + parts; a = ln2(h)
    k_combine_ln<<<TT, 256, 0, stream>>>(h, part, bo + (size_t)L * NE, 2,
         ln2g + (size_t)L * NE, ln2b + (size_t)L * NE, a);
    // ffm = gelu(a @ W1 + b1)
    gemm(stream, a, NE, w1T + (size_t)L * DFF * NE, NE, ffm, DFF, TT, DFF, NE,
         b1 + (size_t)L * DFF, nullptr, 2);
    // ff2: split-K x4 partials
    gemm(stream, ffm, DFF, w2T + (size_t)L * NE * DFF, DFF, part, NE, TT, NE, 768,
         nullptr, nullptr, 3, 4, 768, 768, (long)TT * NE);
    // h += b2 + parts; a = ln1(next) or lnf (last layer)
    const float* gn = (L + 1 < NL) ? ln1g + (size_t)(L + 1) * NE : lnfg;
    const float* bn = (L + 1 < NL) ? ln1b + (size_t)(L + 1) * NE : lnfb;
    k_combine_ln<<<TT, 256, 0, stream>>>(h, part, b2 + (size_t)L * NE, 4, gn, bn, a);
  }
  // logits = a @ Wlm^T  (f32 out) — 256^2 8-wave BK=32 2-blocks/CU GEMM
  k_gemm256<<<dim3(TT / 256, NVP / 256), 512, 0, stream>>>(a, wlmB, (float*)d_out);
}

// Round 19
// 2263.980 us; speedup vs baseline: 1.0642x; 1.0642x over previous
//
#include <hip/hip_runtime.h>
#include <math.h>

typedef unsigned short u16;
typedef u16 u16x8 __attribute__((ext_vector_type(8)));
typedef u16 u16x4 __attribute__((ext_vector_type(4)));
typedef short short8 __attribute__((ext_vector_type(8)));
typedef float f32x4 __attribute__((ext_vector_type(4)));

#define NE 768
#define NH 12
#define NL 12
#define NV 50257
#define NVP 50432   // NV padded to 256 multiple for the 256^2 LM-head GEMM
#define HD 64
#define DFF 3072
#define NB 2
#define SL 1024
#define TT 2048     // NB*SL tokens
#define QKVD 2304   // 3*NE

static __device__ __forceinline__ u16 f2bf(float f){
  unsigned int x; __builtin_memcpy(&x, &f, 4);
  x = (x + 0x7FFFu + ((x >> 16) & 1u)) >> 16;
  return (u16)x;
}

typedef const __attribute__((address_space(1))) unsigned int* gas1_t;
typedef __attribute__((address_space(3))) unsigned int* las3_t;
static __device__ __forceinline__ void gload16(const u16* g, u16* l){
  __builtin_amdgcn_global_load_lds((gas1_t)(const void*)g, (las3_t)(void*)l, 16, 0, 0);
}
// counted vmcnt wait: N loads may remain in flight (wave-uniform arg)
static __device__ __forceinline__ void waitvm(int n){
  switch (n){
    case 0: asm volatile("s_waitcnt vmcnt(0)" ::: "memory"); break;
    case 3: asm volatile("s_waitcnt vmcnt(3)" ::: "memory"); break;
    case 4: asm volatile("s_waitcnt vmcnt(4)" ::: "memory"); break;
    case 6: asm volatile("s_waitcnt vmcnt(6)" ::: "memory"); break;
    case 8: asm volatile("s_waitcnt vmcnt(8)" ::: "memory"); break;
    default: asm volatile("s_waitcnt vmcnt(9)" ::: "memory"); break;
  }
}

// ---------------- fp32 -> bf16 convert (vectorized) ----------------
__global__ void k_cvt4(const float4* __restrict__ in, u16x4* __restrict__ out, long n4){
  long i = (long)blockIdx.x * blockDim.x + threadIdx.x;
  long st = (long)gridDim.x * blockDim.x;
  for (; i < n4; i += st){
    float4 v = in[i];
    u16x4 o = { f2bf(v.x), f2bf(v.y), f2bf(v.z), f2bf(v.w) };
    out[i] = o;
  }
}

// ------ fp32 [L][K][N] -> bf16 [L][N][K] transpose-convert, all layers ------
// Vectorized: float4 reads, u16x4 writes. Tile: 32 K-rows x 128 N-cols.
__global__ __launch_bounds__(256) void k_transpose_cvt_all(const float* __restrict__ in0,
    u16* __restrict__ out0, int K, int N){
  __shared__ u16 tile[128][33];          // [n within 128][k within 32], +1 pad
  const float* in = in0 + (long)blockIdx.z * K * N;
  u16* out = out0 + (long)blockIdx.z * N * K;
  const int n0 = blockIdx.x * 128, k0 = blockIdx.y * 32;
  const int t = threadIdx.x;
#pragma unroll
  for (int i = 0; i < 4; ++i){
    int e = t + i * 256;                 // [0,1024)
    int r = e >> 5, c = e & 31;          // r: k-row [0,32), c: float4 col [0,32)
    float4 v = *(const float4*)(in + (long)(k0 + r) * N + n0 + c * 4);
    tile[c * 4 + 0][r] = f2bf(v.x);
    tile[c * 4 + 1][r] = f2bf(v.y);
    tile[c * 4 + 2][r] = f2bf(v.z);
    tile[c * 4 + 3][r] = f2bf(v.w);
  }
  __syncthreads();
#pragma unroll
  for (int i = 0; i < 4; ++i){
    int e = t + i * 256;                 // [0,1024)
    int nr = e >> 3, kc = e & 7;         // nr: n-row [0,128), kc: u16x4 chunk [0,8)
    u16x4 o = { tile[nr][kc * 4 + 0], tile[nr][kc * 4 + 1],
                tile[nr][kc * 4 + 2], tile[nr][kc * 4 + 3] };
    *(u16x4*)(out + (long)(n0 + nr) * K + k0 + kc * 4) = o;
  }
}

// ---------------- LayerNorm: f32 [TT][768] -> bf16 ----------------
__global__ __launch_bounds__(256) void k_layernorm(const float* __restrict__ x,
    const float* __restrict__ g, const float* __restrict__ b, u16* __restrict__ out){
  int row = blockIdx.x;
  const float* xr = x + (long)row * NE;
  int t = threadIdx.x;
  float v[3];
  v[0] = xr[t]; v[1] = xr[t + 256]; v[2] = xr[t + 512];
  float s = v[0] + v[1] + v[2];
  float sq = v[0]*v[0] + v[1]*v[1] + v[2]*v[2];
  __shared__ float red[8];
#pragma unroll
  for (int o = 32; o; o >>= 1){ s += __shfl_xor(s, o); sq += __shfl_xor(sq, o); }
  int wid = t >> 6, lane = t & 63;
  if (!lane){ red[wid] = s; red[4 + wid] = sq; }
  __syncthreads();
  s  = red[0] + red[1] + red[2] + red[3];
  sq = red[4] + red[5] + red[6] + red[7];
  float mean = s * (1.f / NE);
  float var  = sq * (1.f / NE) - mean * mean;
  float rs = rsqrtf(var + 1e-5f);
  u16* orow = out + (long)row * NE;
#pragma unroll
  for (int i = 0; i < 3; ++i){
    int c = t + i * 256;
    orow[c] = f2bf((v[i] - mean) * rs * g[c] + b[c]);
  }
}

// ---- split-K combine + LayerNorm fused (float4-vectorized): one block/row ----
__global__ __launch_bounds__(256) void k_combine_ln(float* __restrict__ h,
    const float* __restrict__ part, const float* __restrict__ bias, int nsplit,
    const float* __restrict__ g, const float* __restrict__ b, u16* __restrict__ aout){
  const int row = blockIdx.x;
  const int t = threadIdx.x;              // threads 0..191 each own one float4
  float4* hr4 = (float4*)(h + (long)row * NE);
  float4 v = {0.f, 0.f, 0.f, 0.f};
  float s = 0.f, sq = 0.f;
  if (t < NE / 4){
    v = hr4[t];
    float4 bb = ((const float4*)bias)[t];
    v.x += bb.x; v.y += bb.y; v.z += bb.z; v.w += bb.w;
    for (int sp = 0; sp < nsplit; ++sp){
      float4 pv = ((const float4*)(part + (long)sp * TT * NE + (long)row * NE))[t];
      v.x += pv.x; v.y += pv.y; v.z += pv.z; v.w += pv.w;
    }
    hr4[t] = v;
    s  = v.x + v.y + v.z + v.w;
    sq = v.x*v.x + v.y*v.y + v.z*v.z + v.w*v.w;
  }
  __shared__ float red[8];
#pragma unroll
  for (int o = 32; o; o >>= 1){ s += __shfl_xor(s, o); sq += __shfl_xor(sq, o); }
  int wid = t >> 6, lane = t & 63;
  if (!lane){ red[wid] = s; red[4 + wid] = sq; }
  __syncthreads();
  s  = red[0] + red[1] + red[2] + red[3];
  sq = red[4] + red[5] + red[6] + red[7];
  float mean = s * (1.f / NE);
  float var  = sq * (1.f / NE) - mean * mean;
  float rs = rsqrtf(var + 1e-5f);
  if (t < NE / 4){
    float4 gg = ((const float4*)g)[t];
    float4 b2 = ((const float4*)b)[t];
    u16x4 o4 = { f2bf((v.x - mean) * rs * gg.x + b2.x),
                 f2bf((v.y - mean) * rs * gg.y + b2.y),
                 f2bf((v.z - mean) * rs * gg.z + b2.z),
                 f2bf((v.w - mean) * rs * gg.w + b2.w) };
    ((u16x4*)(aout + (long)row * NE))[t] = o4;
  }
}

// ---------------- barrier-free fused causal flash attention ----------------
// 2-wave blocks, 32 q-rows per block, grid (24 bh, 32 q-tiles) heavy-first.
// K-fragments for tile kt+1 prefetched into registers during softmax/PV of kt.
__global__ __launch_bounds__(128) void k_flash(const u16* __restrict__ qkv,
    const u16* __restrict__ vt, u16* __restrict__ out){
  __shared__ u16 Ps[2][16][72];          // wave-private P tile (q x kv)
  const int z = blockIdx.x;
  const int qt = gridDim.y - 1 - blockIdx.y;   // heavy q-tiles dispatch first
  const int b = z / NH, h = z % NH;
  const int t = threadIdx.x, lane = t & 63, wid = t >> 6;
  const int lr = lane & 15, lk = lane >> 4;
  const int qr0 = qt * 32 + wid * 16;    // wave's first q row
  const u16* Qp = qkv + (long)(b * SL + qr0 + lr) * QKVD + h * HD;
  short8 aq[2];
  aq[0] = *(const short8*)(Qp + lk * 8);
  aq[1] = *(const short8*)(Qp + 32 + lk * 8);
  const u16* Kb  = qkv + (long)(b * SL) * QKVD + NE + h * HD;
  const u16* Vtb = vt + (long)z * HD * SL;
  f32x4 o[4] = {};
  float m[4], l[4];
#pragma unroll
  for (int r = 0; r < 4; ++r){ m[r] = -3e38f; l[r] = 0.f; }
  const int nt = (qt * 32 + 31) / 64 + 1;
  // preload K fragments for tile 0
  short8 kb[4][2];
#pragma unroll
  for (int j = 0; j < 4; ++j)
#pragma unroll
    for (int c = 0; c < 2; ++c)
      kb[j][c] = *(const short8*)(Kb + (long)(j * 16 + lr) * QKVD + c * 32 + lk * 8);
  for (int kt = 0; kt < nt; ++kt){
    const int kv0 = kt * 64;
    f32x4 s[4] = {};
#pragma unroll
    for (int c = 0; c < 2; ++c)
#pragma unroll
      for (int j = 0; j < 4; ++j)
        s[j] = __builtin_amdgcn_mfma_f32_16x16x32_bf16(aq[c], kb[j][c], s[j], 0, 0, 0);
    // prefetch next tile's K fragments; loads fly under softmax + PV below
    short8 kbn[4][2];
    if (kt + 1 < nt){
      const int kv1 = kv0 + 64;
#pragma unroll
      for (int j = 0; j < 4; ++j)
#pragma unroll
        for (int c = 0; c < 2; ++c)
          kbn[j][c] = *(const short8*)(Kb + (long)(kv1 + j * 16 + lr) * QKVD + c * 32 + lk * 8);
    }
    const bool dm = (kt == nt - 1);
#pragma unroll
    for (int r = 0; r < 4; ++r){
      const int row = qr0 + lk * 4 + r;
      float pm = -3e38f;
#pragma unroll
      for (int j = 0; j < 4; ++j){
        float v = s[j][r] * 0.125f;
        if (dm && (kv0 + j * 16 + lr > row)) v = -3e38f;
        s[j][r] = v;
        pm = fmaxf(pm, v);
      }
#pragma unroll
      for (int off = 1; off < 16; off <<= 1) pm = fmaxf(pm, __shfl_xor(pm, off));
      float mn = fmaxf(m[r], pm);
      float f = __expf(m[r] - mn);
      m[r] = mn;
      float ps = 0.f;
#pragma unroll
      for (int j = 0; j < 4; ++j){
        float pv = __expf(s[j][r] - mn);
        ps += pv;
        Ps[wid][lk * 4 + r][j * 16 + lr] = f2bf(pv);
      }
#pragma unroll
      for (int off = 1; off < 16; off <<= 1) ps += __shfl_xor(ps, off);
      l[r] = l[r] * f + ps;
#pragma unroll
      for (int j = 0; j < 4; ++j) o[j][r] *= f;
    }
#pragma unroll
    for (int c = 0; c < 2; ++c){
      short8 pa = *(const short8*)&Ps[wid][lr][c * 32 + lk * 8];
#pragma unroll
      for (int j = 0; j < 4; ++j){
        short8 vb = *(const short8*)(Vtb + (long)(j * 16 + lr) * SL + kv0 + c * 32 + lk * 8);
        o[j] = __builtin_amdgcn_mfma_f32_16x16x32_bf16(pa, vb, o[j], 0, 0, 0);
      }
    }
    if (kt + 1 < nt){
#pragma unroll
      for (int j = 0; j < 4; ++j)
#pragma unroll
        for (int c = 0; c < 2; ++c)
          kb[j][c] = kbn[j][c];
    }
  }
  u16* O = out + (long)(b * SL) * NE + h * HD;
#pragma unroll
  for (int r = 0; r < 4; ++r){
    float inv = 1.f / l[r];
    const int row = qr0 + lk * 4 + r;
#pragma unroll
    for (int j = 0; j < 4; ++j)
      O[(long)row * NE + j * 16 + lr] = f2bf(o[j][r] * inv);
  }
}

// --- generic bf16 MFMA GEMM, 64x128 tile, B^T layout, 4-buf (depth-3) ring ---
// Parity-aware LDS swizzle: slot ^= (row>>1)&3 on both stage-source and read.
// modes: 2 bf16 +bias +gelu(erf), 3 f32 raw, 5 qkv: bf16 +bias, V cols scattered to vt
struct GemmP {
  const u16* A; const u16* B; void* C;
  const float* bias; u16* vt;
  int M, N, K, lda, ldb, ldc, mode;
  long zA, zB, zC;                       // per-blockIdx.z element offsets (split-K)
};

__global__ __launch_bounds__(256) void k_gemm_bt(GemmP p){
  __shared__ u16 As[4][64 * 32];
  __shared__ u16 Bs[4][128 * 32];
  // XCD-aware block swizzle (nwg is always a multiple of 8 here)
  const int nwg = gridDim.x * gridDim.y;
  const int orig = blockIdx.x + blockIdx.y * gridDim.x;
  const int wg = (orig & 7) * (nwg >> 3) + (orig >> 3);
  const int m0 = (wg % gridDim.x) * 64, n0 = (wg / gridDim.x) * 128;
  const u16* A = p.A + (long)blockIdx.z * p.zA;
  const u16* B = p.B + (long)blockIdx.z * p.zB;
  const long offC = (long)blockIdx.z * p.zC;
  const int t = threadIdx.x, lane = t & 63, wid = t >> 6;
  const int wm = (wid >> 1) * 32, wn = (wid & 1) * 64;
  const int lr = lane & 15, lk = lane >> 4;
  const int srow = t >> 2;               // [0,64)
  // pre-swizzled source slot: phys slot (t&3) holds logical slot (t&3)^((srow>>1)&3)
  const int sseg = ((t & 3) ^ ((srow >> 1) & 3)) * 8;
  const u16* Abase  = A + (long)(m0 + srow) * p.lda + sseg;
  const u16* Bbase  = B + (long)(n0 + srow) * p.ldb + sseg;
  const u16* Bbase2 = B + (long)(n0 + 64 + srow) * p.ldb + sseg;  // (row+64): same XOR
  auto stage = [&](int buf, int kt){     // 3 gload_lds per thread per K-tile
    gload16(Abase  + kt * 32, &As[buf][t * 8]);
    gload16(Bbase  + kt * 32, &Bs[buf][t * 8]);
    gload16(Bbase2 + kt * 32, &Bs[buf][(t + 256) * 8]);
  };
  f32x4 acc[2][4] = {};
  const int nk = p.K >> 5;               // always >= 2 here
  stage(0, 0);
  stage(1, 1);
  if (nk > 2) stage(2, 2);
  for (int kt = 0; kt < nk; ++kt){
    const int cur = kt & 3;
    if (kt + 3 < nk) stage((kt + 3) & 3, kt + 3);  // overwrite of (kt-1)&3: guarded
    // wait only this tile's 3 loads; leave up to 9 (tiles kt+1..kt+3) in flight
    int rem = nk - 1 - kt;
    waitvm(rem >= 3 ? 9 : rem == 2 ? 6 : rem == 1 ? 3 : 0);
    __builtin_amdgcn_s_barrier();        // all waves' tile-kt loads complete
    short8 af[2], bfr[4];
#pragma unroll
    for (int i = 0; i < 2; ++i){
      int r = wm + i * 16 + lr;
      af[i]  = *(const short8*)&As[cur][r * 32 + ((lk ^ ((r >> 1) & 3)) * 8)];
    }
#pragma unroll
    for (int j = 0; j < 4; ++j){
      int r = wn + j * 16 + lr;
      bfr[j] = *(const short8*)&Bs[cur][r * 32 + ((lk ^ ((r >> 1) & 3)) * 8)];
    }
#pragma unroll
    for (int i = 0; i < 2; ++i)
#pragma unroll
      for (int j = 0; j < 4; ++j)
        acc[i][j] = __builtin_amdgcn_mfma_f32_16x16x32_bf16(af[i], bfr[j], acc[i][j], 0, 0, 0);
    asm volatile("s_waitcnt lgkmcnt(0)" ::: "memory");  // ds_reads of buf done
    __builtin_amdgcn_s_barrier();        // before buf is restaged (3 iters later)
  }
#pragma unroll
  for (int i = 0; i < 2; ++i){
#pragma unroll
    for (int r = 0; r < 4; ++r){
      int row = m0 + wm + i * 16 + lk * 4 + r;
      if (row >= p.M) continue;
#pragma unroll
      for (int j = 0; j < 4; ++j){
        int col = n0 + wn + j * 16 + lr;
        if (col >= p.N) continue;
        float v = acc[i][j][r];
        long idx = offC + (long)row * p.ldc + col;
        if (p.mode == 5){
          v += p.bias[col];
          if (col >= 2 * NE){
            int d = col - 2 * NE;
            long vidx = (((long)(row >> 10) * NH + (d >> 6)) * HD + (d & 63)) * SL + (row & 1023);
            p.vt[vidx] = f2bf(v);
          } else {
            ((u16*)p.C)[idx] = f2bf(v);
          }
        } else if (p.mode == 2){
          v += p.bias[col];
          v = 0.5f * v * (1.f + erff(v * 0.70710678118f));
          ((u16*)p.C)[idx] = f2bf(v);
        } else {
          ((float*)p.C)[idx] = v;
        }
      }
    }
  }
}

static inline void gemm(hipStream_t s, const u16* A, int lda, const u16* B, int ldb,
    void* C, int ldc, int M, int N, int K, const float* bias, u16* vt, int mode,
    int gz = 1, long zA = 0, long zB = 0, long zC = 0){
  GemmP p{ A, B, C, bias, vt, M, N, K, lda, ldb, ldc, mode, zA, zB, zC };
  dim3 g(M / 64, (N + 127) / 128, gz);
  k_gemm_bt<<<g, 256, 0, s>>>(p);
}

// ======== 256x256 8-wave LM-head GEMM (r17-proven): BK=64, 2-buf depth-1 ========
// T2 XOR-swizzled LDS (linear gload_lds dest + pre-swizzled global src, rule #21),
// T4 counted vmcnt(8) across barriers, T5 setprio around MFMA clusters.
__global__ __launch_bounds__(512, 1) void k_gemm256(const u16* __restrict__ A,
    const u16* __restrict__ B, float* __restrict__ C){
  __shared__ u16 As[2][256 * 64];
  __shared__ u16 Bs[2][256 * 64];
  const int gx = gridDim.x, nwg = gx * gridDim.y;
  const int orig = blockIdx.x + blockIdx.y * gx;
  const int wg = (orig & 7) * (nwg >> 3) + (orig >> 3);   // nwg % 8 == 0
  const int m0 = (wg % gx) * 256, n0 = (wg / gx) * 256;
  const int t = threadIdx.x, lane = t & 63;
  const int lr = lane & 15, lk = lane >> 4;
  const int wid = t >> 6, wr = wid >> 2, wc = wid & 3;    // wave tile 128x64
  // staging: load i covers physical LDS bytes tt*16 (tt = t + i*512):
  // row r = tt>>3, phys slot p = tt&7; fetch logical slot p^(r&7) (swizzle involution)
  const u16* gA[4]; const u16* gB[4]; int ldst[4];
#pragma unroll
  for (int i = 0; i < 4; ++i){
    int tt = t + i * 512, r = tt >> 3, pp = tt & 7, sl = pp ^ (r & 7);
    gA[i] = A + (long)(m0 + r) * NE + sl * 8;
    gB[i] = B + (long)(n0 + r) * NE + sl * 8;
    ldst[i] = tt * 8;                    // u16 offset
  }
  auto stage = [&](int buf, int kt){     // 8 gload16 per thread
#pragma unroll
    for (int i = 0; i < 4; ++i) gload16(gA[i] + kt * 64, &As[buf][ldst[i]]);
#pragma unroll
    for (int i = 0; i < 4; ++i) gload16(gB[i] + kt * 64, &Bs[buf][ldst[i]]);
  };
  // swizzled fragment reads: logical u16 col (kc*32+lk*8) ^ ((row&7)<<3)
  f32x4 acc[8][4] = {};
  const int nk = NE / 64;                // 12 K-tiles
  stage(0, 0);
  for (int kt = 0; kt < nk; ++kt){
    const int buf = kt & 1;
    if (kt + 1 < nk){ stage(buf ^ 1, kt + 1); waitvm(8); }
    else            { waitvm(0); }
    __builtin_amdgcn_sched_barrier(0);
    __builtin_amdgcn_s_barrier();        // tile kt resident in As/Bs[buf]
    __builtin_amdgcn_sched_barrier(0);
    short8 bf[4][2];
#pragma unroll
    for (int nj = 0; nj < 4; ++nj)
#pragma unroll
      for (int kc = 0; kc < 2; ++kc){
        int r = wc * 64 + nj * 16 + lr;
        bf[nj][kc] = *(const short8*)&Bs[buf][r * 64 + ((kc * 32 + lk * 8) ^ ((r & 7) << 3))];
      }
    {
      short8 af[4][2];
#pragma unroll
      for (int mi = 0; mi < 4; ++mi)
#pragma unroll
        for (int kc = 0; kc < 2; ++kc){
          int r = wr * 128 + mi * 16 + lr;
          af[mi][kc] = *(const short8*)&As[buf][r * 64 + ((kc * 32 + lk * 8) ^ ((r & 7) << 3))];
        }
      __builtin_amdgcn_s_setprio(1);
#pragma unroll
      for (int mi = 0; mi < 4; ++mi)
#pragma unroll
        for (int nj = 0; nj < 4; ++nj)
#pragma unroll
          for (int kc = 0; kc < 2; ++kc)
            acc[mi][nj] = __builtin_amdgcn_mfma_f32_16x16x32_bf16(af[mi][kc], bf[nj][kc], acc[mi][nj], 0, 0, 0);
      __builtin_amdgcn_s_setprio(0);
    }
    {
      short8 af[4][2];
#pragma unroll
      for (int mi = 0; mi < 4; ++mi)
#pragma unroll
        for (int kc = 0; kc < 2; ++kc){
          int r = wr * 128 + (mi + 4) * 16 + lr;
          af[mi][kc] = *(const short8*)&As[buf][r * 64 + ((kc * 32 + lk * 8) ^ ((r & 7) << 3))];
        }
      __builtin_amdgcn_s_setprio(1);
#pragma unroll
      for (int mi = 0; mi < 4; ++mi)
#pragma unroll
        for (int nj = 0; nj < 4; ++nj)
#pragma unroll
          for (int kc = 0; kc < 2; ++kc)
            acc[mi + 4][nj] = __builtin_amdgcn_mfma_f32_16x16x32_bf16(af[mi][kc], bf[nj][kc], acc[mi + 4][nj], 0, 0, 0);
      __builtin_amdgcn_s_setprio(0);
    }
    asm volatile("s_waitcnt lgkmcnt(0)" ::: "memory");  // this wave's ds_reads of buf done
    __builtin_amdgcn_sched_barrier(0);
    __builtin_amdgcn_s_barrier();        // all waves done with buf -> restage next iter
  }
#pragma unroll
  for (int mi = 0; mi < 8; ++mi)
#pragma unroll
    for (int r = 0; r < 4; ++r){
      int row = m0 + wr * 128 + mi * 16 + lk * 4 + r;
#pragma unroll
      for (int nj = 0; nj < 4; ++nj){
        int col = n0 + wc * 64 + nj * 16 + lr;
        if (col < NV) C[(long)row * NV + col] = acc[mi][nj][r];
      }
    }
}

extern "C" void kernel_launch(void* const* d_in, const int* in_sizes, int n_in,
                              void* d_out, int out_size, void* d_ws, size_t ws_size,
                              hipStream_t stream){
  (void)in_sizes; (void)n_in; (void)out_size; (void)ws_size;
  const float* x    = (const float*)d_in[0];
  const float* Wqkv = (const float*)d_in[1];
  const float* bqkv = (const float*)d_in[2];
  const float* Wo   = (const float*)d_in[3];
  const float* bo   = (const float*)d_in[4];
  const float* W1   = (const float*)d_in[5];
  const float* b1   = (const float*)d_in[6];
  const float* W2   = (const float*)d_in[7];
  const float* b2   = (const float*)d_in[8];
  const float* ln1g = (const float*)d_in[9];
  const float* ln1b = (const float*)d_in[10];
  const float* ln2g = (const float*)d_in[11];
  const float* ln2b = (const float*)d_in[12];
  const float* lnfg = (const float*)d_in[13];
  const float* lnfb = (const float*)d_in[14];
  const float* Wlm  = (const float*)d_in[15];

  char* ws = (char*)d_ws;
  size_t off = 0;
  auto alloc = [&](size_t bytes){ void* p = ws + off; off += (bytes + 255) & ~255UL; return p; };
  float* h      = (float*)alloc((size_t)TT * NE * 4);
  u16*   a      = (u16*)  alloc((size_t)TT * NE * 2);
  u16*   qkv    = (u16*)  alloc((size_t)TT * QKVD * 2);
  u16*   vtbuf  = (u16*)  alloc((size_t)NB * NH * HD * SL * 2);
  u16*   attno  = (u16*)  alloc((size_t)TT * NE * 2);
  u16*   ffm    = (u16*)  alloc((size_t)TT * DFF * 2);
  float* part   = (float*)alloc((size_t)4 * TT * NE * 4);
  u16*   wqkvT  = (u16*)  alloc((size_t)NL * QKVD * NE * 2);
  u16*   woT    = (u16*)  alloc((size_t)NL * NE * NE * 2);
  u16*   w1T    = (u16*)  alloc((size_t)NL * DFF * NE * 2);
  u16*   w2T    = (u16*)  alloc((size_t)NL * NE * DFF * 2);
  u16*   wlmB   = (u16*)  alloc((size_t)NVP * NE * 2);

  // h = x
  hipMemcpyAsync(h, x, (size_t)TT * NE * 4, hipMemcpyDeviceToDevice, stream);
  // weight conversions (vectorized transpose: grid N/128 x K/32 x NL)
  k_transpose_cvt_all<<<dim3(QKVD / 128, NE / 32, NL), 256, 0, stream>>>(Wqkv, wqkvT, NE, QKVD);
  k_transpose_cvt_all<<<dim3(NE / 128, NE / 32, NL),   256, 0, stream>>>(Wo,   woT,   NE, NE);
  k_transpose_cvt_all<<<dim3(DFF / 128, NE / 32, NL),  256, 0, stream>>>(W1,   w1T,   NE, DFF);
  k_transpose_cvt_all<<<dim3(NE / 128, DFF / 32, NL),  256, 0, stream>>>(W2,   w2T,   DFF, NE);
  k_cvt4<<<2048, 256, 0, stream>>>((const float4*)Wlm, (u16x4*)wlmB, (long)NV * NE / 4);
  hipMemsetAsync(wlmB + (size_t)NV * NE, 0, (size_t)(NVP - NV) * NE * 2, stream);

  // ln1 of layer 0
  k_layernorm<<<TT, 256, 0, stream>>>(h, ln1g, ln1b, a);

  for (int L = 0; L < NL; ++L){
    // qkv = a @ Wqkv + bqkv ; V columns scattered transposed into vtbuf
    gemm(stream, a, NE, wqkvT + (size_t)L * QKVD * NE, NE, qkv, QKVD, TT, QKVD, NE,
         bqkv + (size_t)L * QKVD, vtbuf, 5);
    // fused causal attention -> attno
    k_flash<<<dim3(NB * NH, SL / 32), 128, 0, stream>>>(qkv, vtbuf, attno);
    // proj: split-K x2 partials
    gemm(stream, attno, NE, woT + (size_t)L * NE * NE, NE, part, NE, TT, NE, 384,
         nullptr, nullptr, 3, 2, 384, 384, (long)TT * NE);
    // h += bo + parts; a = ln2(h)
    k_combine_ln<<<TT, 256, 0, stream>>>(h, part, bo + (size_t)L * NE, 2,
         ln2g + (size_t)L * NE, ln2b + (size_t)L * NE, a);
    // ffm = gelu(a @ W1 + b1)
    gemm(stream, a, NE, w1T + (size_t)L * DFF * NE, NE, ffm, DFF, TT, DFF, NE,
         b1 + (size_t)L * DFF, nullptr, 2);
    // ff2: split-K x4 partials
    gemm(stream, ffm, DFF, w2T + (size_t)L * NE * DFF, DFF, part, NE, TT, NE, 768,
         nullptr, nullptr, 3, 4, 768, 768, (long)TT * NE);
    // h += b2 + parts; a = ln1(next) or lnf (last layer)
    const float* gn = (L + 1 < NL) ? ln1g + (size_t)(L + 1) * NE : lnfg;
    const float* bn = (L + 1 < NL) ? ln1b + (size_t)(L + 1) * NE : lnfb;
    k_combine_ln<<<TT, 256, 0, stream>>>(h, part, b2 + (size_t)L * NE, 4, gn, bn, a);
  }
  // logits = a @ Wlm^T  (f32 out) — 256^2 8-wave pipelined GEMM
  k_gemm256<<<dim3(TT / 256, NVP / 256), 512, 0, stream>>>(a, wlmB, (float*)d_out);
}